// Round 12
// baseline (3133.859 us; speedup 1.0000x reference)
//
#include <hip/hip_runtime.h>
#include <hip/hip_bf16.h>

typedef float   f32x4_t  __attribute__((ext_vector_type(4)));
typedef float   f32x2_t  __attribute__((ext_vector_type(2)));
typedef __bf16  bf16x8_t __attribute__((ext_vector_type(8)));
typedef int     i32x4_t  __attribute__((ext_vector_type(4)));

#define N_ROWS   16384
#define N_COLS   1000
#define N_COLS_P 1024
#define N_DIM    512
#define N_ITER   100
#define PBLK     256
#define PTHR     512
#define SLOTF    4096      /* floats per ktu slot: 1024 cols x 4 (64B/4cols) */

// ---- control plane ----
__device__ __forceinline__ int ldi_sc1(const int* p) {
    return __hip_atomic_load(p, __ATOMIC_RELAXED, __HIP_MEMORY_SCOPE_AGENT);
}
__device__ __forceinline__ void addi_sc1(int* p) {
    __hip_atomic_fetch_add(p, 1, __ATOMIC_RELAXED, __HIP_MEMORY_SCOPE_AGENT);
}
// ---- data plane ----
__device__ __forceinline__ void addf_sc1(float* p, float v) {
    __hip_atomic_fetch_add(p, v, __ATOMIC_RELAXED, __HIP_MEMORY_SCOPE_AGENT);
}
__device__ __forceinline__ void ld2x1_coh(const float* p0, const float* p1,
                                          float* a, float* b) {
    asm volatile("global_load_dword %0, %2, off sc0 sc1\n\t"
                 "global_load_dword %1, %3, off sc0 sc1\n\t"
                 "s_waitcnt vmcnt(0)"
                 : "=&v"(*a), "=&v"(*b) : "v"(p0), "v"(p1) : "memory");
}
__device__ __forceinline__ void drain_vmem() {
    asm volatile("s_waitcnt vmcnt(0)" ::: "memory");
}

__device__ __forceinline__ unsigned short f2bf(float f) {
    unsigned int u = __builtin_bit_cast(unsigned int, f);
    u += 0x7FFFu + ((u >> 16) & 1u);            // RNE round to bf16
    return (unsigned short)(u >> 16);
}

// ---------------------------------------------------------------------------
// GEMM pass (unchanged, proven): dot = F @ T^T ; K = exp(-2*s/(1-s)), s=2*dot.
// MODE 0: K bf16 (stride 1024, zero-pad) into d_out + column partial sums.
// MODE 1: final plan out[i][j] = u[i]*K[i][j]*v[j] (f32, stride 1000).
// ---------------------------------------------------------------------------
template <int MODE>
__launch_bounds__(256)
__global__ void k_gemm(const float* __restrict__ F, const float* __restrict__ T,
                       void* __restrict__ Kout, float* __restrict__ cpart,
                       const float* __restrict__ v_com, const float* __restrict__ u_both,
                       const int* __restrict__ flags)
{
    __shared__ unsigned short lA[128 * 72];
    __shared__ unsigned short lB[128 * 72];
    __shared__ float cs_lds[4 * 64];

    const int bm = blockIdx.x;
    const int bn = blockIdx.y;
    const int m0 = bm << 7;
    const int n0 = bn << 7;
    const int t  = threadIdx.x;
    const int lane = t & 63;
    const int wid  = t >> 6;
    const int wr = wid >> 1;
    const int wc = wid & 1;

    f32x4_t acc[4][4];
#pragma unroll
    for (int a = 0; a < 4; ++a)
#pragma unroll
        for (int b = 0; b < 4; ++b)
            acc[a][b] = (f32x4_t){0.f, 0.f, 0.f, 0.f};

    const int srow = t >> 4;
    const int scol = (t & 15) << 2;

    for (int kt = 0; kt < N_DIM; kt += 64) {
#pragma unroll
        for (int r = 0; r < 8; ++r) {
            const int rr = srow + (r << 4);
            const float4 av = *(const float4*)(F + (size_t)(m0 + rr) * N_DIM + kt + scol);
            ushort4 a4; a4.x = f2bf(av.x); a4.y = f2bf(av.y); a4.z = f2bf(av.z); a4.w = f2bf(av.w);
            *(ushort4*)(&lA[rr * 72 + scol]) = a4;
            const int gn = n0 + rr;
            float4 bv = make_float4(0.f, 0.f, 0.f, 0.f);
            if (gn < N_COLS) bv = *(const float4*)(T + (size_t)gn * N_DIM + kt + scol);
            ushort4 b4; b4.x = f2bf(bv.x); b4.y = f2bf(bv.y); b4.z = f2bf(bv.z); b4.w = f2bf(bv.w);
            *(ushort4*)(&lB[rr * 72 + scol]) = b4;
        }
        __syncthreads();
#pragma unroll
        for (int ks = 0; ks < 2; ++ks) {
            bf16x8_t afr[4], bfr[4];
#pragma unroll
            for (int mf = 0; mf < 4; ++mf) {
                const int r = (wr << 6) + (mf << 4) + (lane & 15);
                const int off = r * 72 + (ks << 5) + ((lane >> 4) << 3);
                afr[mf] = __builtin_bit_cast(bf16x8_t, *(const i32x4_t*)(&lA[off]));
            }
#pragma unroll
            for (int nf = 0; nf < 4; ++nf) {
                const int r = (wc << 6) + (nf << 4) + (lane & 15);
                const int off = r * 72 + (ks << 5) + ((lane >> 4) << 3);
                bfr[nf] = __builtin_bit_cast(bf16x8_t, *(const i32x4_t*)(&lB[off]));
            }
#pragma unroll
            for (int mf = 0; mf < 4; ++mf)
#pragma unroll
                for (int nf = 0; nf < 4; ++nf)
                    acc[mf][nf] = __builtin_amdgcn_mfma_f32_16x16x32_bf16(
                        afr[mf], bfr[nf], acc[mf][nf], 0, 0, 0);
        }
        __syncthreads();
    }

    int usel = 2;
    if (MODE == 1) usel = flags[1];
    float csum[4] = {0.f, 0.f, 0.f, 0.f};
#pragma unroll
    for (int mf = 0; mf < 4; ++mf) {
#pragma unroll
        for (int nf = 0; nf < 4; ++nf) {
#pragma unroll
            for (int j = 0; j < 4; ++j) {
                const float d = acc[mf][nf][j];
                const float s = 2.f * d;
                const float M = s / (1.f - s);
                const float kv = __expf(-2.f * M);
                const int grow = m0 + (wr << 6) + (mf << 4) + ((lane >> 4) << 2) + j;
                const int gcol = n0 + (wc << 6) + (nf << 4) + (lane & 15);
                if (MODE == 0) {
                    ((unsigned short*)Kout)[(size_t)grow * N_COLS_P + gcol] =
                        (gcol < N_COLS) ? f2bf(kv) : (unsigned short)0;
                    csum[nf] += kv;
                } else {
                    if (gcol < N_COLS) {
                        const float u = (usel == 2) ? (1.f / 16384.f)
                                                    : u_both[(size_t)usel * N_ROWS + grow];
                        ((float*)Kout)[(size_t)grow * N_COLS + gcol] = u * kv * v_com[gcol];
                    }
                }
            }
        }
    }
    if (MODE == 0) {
#pragma unroll
        for (int nf = 0; nf < 4; ++nf) {
            csum[nf] += __shfl_xor(csum[nf], 16);
            csum[nf] += __shfl_xor(csum[nf], 32);
        }
        if (lane < 16) {
#pragma unroll
            for (int nf = 0; nf < 4; ++nf)
                cs_lds[wid * 64 + (nf << 4) + lane] = csum[nf];
        }
        __syncthreads();
        if (t < 128) {
            const int cw = t >> 6;
            const int c6 = t & 63;
            cpart[(size_t)bm * N_COLS_P + n0 + t] =
                cs_lds[cw * 64 + c6] + cs_lds[(cw + 2) * 64 + c6];
        }
    }
}

// ---------------------------------------------------------------------------
// init1: ktu0 = colsum(K)/16384 from cpart (aliases slots base; read BEFORE
// init2 zeroes the region). Pads = 1.0.
// ---------------------------------------------------------------------------
__launch_bounds__(128)
__global__ void k_init1(const float* __restrict__ cpart, float* __restrict__ ktu0)
{
    const int j = blockIdx.x * 128 + threadIdx.x;   // 0..1023
    if (j < N_COLS) {
        float s = 0.f;
        for (int p = 0; p < 128; ++p) s += cpart[(size_t)p * N_COLS_P + j];
        ktu0[j] = s * (1.f / 16384.f);
    } else {
        ktu0[j] = 1.f;
    }
}

// ---------------------------------------------------------------------------
// init2: zero the 100 ktu slots (pads seeded to 1.0), zero done counters and
// flags. Runs every call => graph replays are state-clean.
// Slot layout: slot s, column j at slots[s*4096 + j*4] (4 cols / 64B line).
// ---------------------------------------------------------------------------
__launch_bounds__(256)
__global__ void k_init2(float* __restrict__ slots, int* __restrict__ done,
                        int* __restrict__ flags)
{
    const int idx = blockIdx.x * 256 + threadIdx.x;   // f32x4 group index
    if (idx < N_ITER * 1024) {                         // 1024 groups per slot
        f32x4_t v = (f32x4_t){0.f, 0.f, 0.f, 0.f};
        if ((idx & 1023) >= N_COLS) v[0] = 1.f;        // pad column = 1.0
        *(f32x4_t*)&slots[(size_t)idx << 2] = v;
    }
    if (blockIdx.x == 0) {
        for (int z = threadIdx.x; z < N_ITER * 16; z += 256) done[z] = 0;
        if (threadIdx.x < 16) flags[threadIdx.x] = (threadIdx.x == 1) ? 2 : 0;
    }
}

// ---------------------------------------------------------------------------
// Persistent Sinkhorn — ONE sync hop per iteration via atomic fan-in.
// 256 blocks x 512 thr. Thread t owns columns {2t, 2t+1}.
// iter ii: top: poll done[ii-1]==256 (1 lane, 1 line); read slot(ii-1)
//          coherently; nonfinite => bad(ii-1), break before commit; commit;
//          every-10 convergence check (uniform: same bits everywhere).
//          A: v=b/ktu; dots; u; per-block col sums via LDS; 2 atomicAdds
//          into slot ii; vmcnt(0); bump done[ii].
// Bad-u poisons the slot organically (NaN/Inf through the adds).
// ---------------------------------------------------------------------------
__launch_bounds__(PTHR, 2)
__global__ void k_persist(const unsigned short* __restrict__ Kb,
                          const float* __restrict__ ratios,
                          const float* __restrict__ ktu0,   // [1024]
                          float* __restrict__ slots,        // [100][4096]
                          float* __restrict__ utmp,         // [2][16384]
                          float* __restrict__ vcom,         // [1024]
                          int* __restrict__ flags,
                          int* __restrict__ done)           // [100*16]
{
    __shared__ float vbuf[2][N_COLS_P];
    __shared__ float wp[8][N_COLS_P];
    __shared__ float cw[8];
    __shared__ float rbc;
    const int t = threadIdx.x, lane = t & 63, wid = t >> 6, b = blockIdx.x;
    const int row0 = (b << 6) + (wid << 3);
    const int c2 = t << 1;

    // K preload: packed bf16 pairs, coalesced dword loads (read-only, cached).
    unsigned kp[8][8];
#pragma unroll
    for (int r = 0; r < 8; ++r) {
        const unsigned* rp = (const unsigned*)(Kb + (size_t)(row0 + r) * N_COLS_P);
#pragma unroll
        for (int q = 0; q < 8; ++q) kp[r][q] = rp[(q << 6) + lane];
    }
    const float bj0 = (c2 < N_COLS) ? ratios[c2] * 16384.f : 0.f;
    const float bj1 = (c2 + 1 < N_COLS) ? ratios[c2 + 1] * 16384.f : 0.f;

    int usel = 2;

    for (int ii = 0; ii <= N_ITER; ++ii) {
        const int sp = ii & 1;
        float kc0, kc1;

        if (ii > 0) {
            // ---- top: single-lane poll of done counter (the ONE hop) ----
            if (t == 0) {
                while (ldi_sc1(&done[(ii - 1) << 4]) < PBLK)
                    __builtin_amdgcn_s_sleep(1);
            }
            __syncthreads();
            const float* sl = slots + (size_t)(ii - 1) * SLOTF;
            ld2x1_coh(sl + (size_t)c2 * 4, sl + (size_t)c2 * 4 + 4, &kc0, &kc1);
            const int badk = (!isfinite(kc0)) | (!isfinite(kc1));
            if (__syncthreads_or(badk)) break;   // u(ii-1) bad: revert, no commit
            usel = (ii - 1) & 1;                 // commit iter ii-1
            if (((ii - 1) % 10) == 0) {          // convergence check of iter ii-1
                const float vo0 = vbuf[usel][c2], vo1 = vbuf[usel][c2 + 1];
                const float d0 = (c2 < N_COLS) ? kc0 * vo0 - bj0 : 0.f;
                const float d1 = (c2 + 1 < N_COLS) ? kc1 * vo1 - bj1 : 0.f;
                float e = d0 * d0 + d1 * d1;
#pragma unroll
                for (int sh = 1; sh <= 32; sh <<= 1) e += __shfl_xor(e, sh);
                if (lane == 0) cw[wid] = e;
                __syncthreads();
                if (t == 0) {
                    float s = 0.f;
#pragma unroll
                    for (int w = 0; w < 8; ++w) s += cw[w];
                    rbc = s;
                }
                __syncthreads();
                if (rbc < 1e-18f) break;         // converged (committed)
            }
            if (ii == N_ITER) break;             // epilogue-only pass
        } else {
            kc0 = ktu0[c2];
            kc1 = ktu0[c2 + 1];
        }

        // ---- phase A ----
        const float v0 = bj0 / kc0;
        const float v1 = bj1 / kc1;
        const int badv = (kc0 == 0.f) | (kc1 == 0.f) |
                         (!isfinite(v0)) | (!isfinite(v1));
        vbuf[sp][c2] = v0; vbuf[sp][c2 + 1] = v1;
        if (__syncthreads_or(badv)) break;       // uniform: revert to ii-1 state

        float vr[16];
#pragma unroll
        for (int q = 0; q < 8; ++q) {
            const f32x2_t vv = *(const f32x2_t*)&vbuf[sp][(q << 7) + (lane << 1)];
            vr[2*q] = vv[0]; vr[2*q+1] = vv[1];
        }
        float dots[8];
#pragma unroll
        for (int r = 0; r < 8; ++r) {
            float p0 = 0.f, p1 = 0.f, p2 = 0.f, p3 = 0.f;
#pragma unroll
            for (int q = 0; q < 8; ++q) {
                const unsigned u = kp[r][q];
                const float lo = __builtin_bit_cast(float, u << 16);
                const float hi = __builtin_bit_cast(float, u & 0xFFFF0000u);
                if (q & 1) { p2 = fmaf(lo, vr[2*q], p2); p3 = fmaf(hi, vr[2*q+1], p3); }
                else       { p0 = fmaf(lo, vr[2*q], p0); p1 = fmaf(hi, vr[2*q+1], p1); }
            }
            dots[r] = (p0 + p1) + (p2 + p3);
        }
#pragma unroll
        for (int s = 1; s <= 32; s <<= 1) {
#pragma unroll
            for (int r = 0; r < 8; ++r) dots[r] += __shfl_xor(dots[r], s);
        }
        float u8[8];
#pragma unroll
        for (int r = 0; r < 8; ++r) u8[r] = 1.f / dots[r];   // nonfinite u poisons
        if (lane == 0) {                                      // the slot organically
            float* uo = utmp + ((size_t)sp << 14) + row0;
#pragma unroll
            for (int r = 0; r < 8; ++r) uo[r] = u8[r];
        }

        float creg[16];
#pragma unroll
        for (int e = 0; e < 16; ++e) creg[e] = 0.f;
#pragma unroll
        for (int r = 0; r < 8; ++r) {
#pragma unroll
            for (int q = 0; q < 8; ++q) {
                const unsigned u = kp[r][q];
                const float lo = __builtin_bit_cast(float, u << 16);
                const float hi = __builtin_bit_cast(float, u & 0xFFFF0000u);
                creg[2*q]   = fmaf(lo, u8[r], creg[2*q]);
                creg[2*q+1] = fmaf(hi, u8[r], creg[2*q+1]);
            }
        }
#pragma unroll
        for (int q = 0; q < 8; ++q)
            *(f32x2_t*)&wp[wid][(q << 7) + (lane << 1)] = (f32x2_t){creg[2*q], creg[2*q+1]};
        __syncthreads();
        {
            const int j2 = t << 1;
            f32x2_t s2 = *(const f32x2_t*)&wp[0][j2];
#pragma unroll
            for (int w = 1; w < 8; ++w) {
                const f32x2_t x = *(const f32x2_t*)&wp[w][j2];
                s2[0] += x[0]; s2[1] += x[1];
            }
            float* sl = slots + (size_t)ii * SLOTF;
            if (j2 < N_COLS)     addf_sc1(sl + (size_t)j2 * 4, s2[0]);
            if (j2 + 1 < N_COLS) addf_sc1(sl + (size_t)(j2 + 1) * 4, s2[1]);
        }
        drain_vmem();                     // adds + utmp stores globally performed
        __syncthreads();
        if (t == 0) addi_sc1(&done[ii << 4]);
    }

    // ---- epilogue: block 0 materializes committed v and u_sel ----
    if (b == 0) {
        if (c2 < N_COLS)
            vcom[c2] = (usel == 2) ? (1.f / 1000.f) : vbuf[usel][c2];
        if (c2 + 1 < N_COLS)
            vcom[c2 + 1] = (usel == 2) ? (1.f / 1000.f) : vbuf[usel][c2 + 1];
        if (t == 0) flags[1] = usel;
    }
}

extern "C" void kernel_launch(void* const* d_in, const int* in_sizes, int n_in,
                              void* d_out, int out_size, void* d_ws, size_t ws_size,
                              hipStream_t stream)
{
    const float* F      = (const float*)d_in[0];
    const float* T      = (const float*)d_in[1];
    const float* ratios = (const float*)d_in[2];
    float* out = (float*)d_out;
    unsigned short* Kb = (unsigned short*)d_out;   // bf16 K, stride 1024

    float* ws        = (float*)d_ws;
    float* slots     = ws;                                   // 100*4096 floats
    float* cpart     = slots;                                // alias (pre-init2)
    float* ktu0      = slots + (size_t)N_ITER * SLOTF;       // 1024
    float* utmp      = ktu0 + N_COLS_P;                      // 2*16384
    float* vcom      = utmp + 2 * N_ROWS;                    // 1024
    int*   flags     = (int*)(vcom + N_COLS_P);              // 16
    int*   done      = flags + 16;                           // 100*16
    const size_t need_bytes = ((size_t)N_ITER * SLOTF + N_COLS_P + 2 * N_ROWS +
                               N_COLS_P) * sizeof(float) +
                              (16 + N_ITER * 16) * sizeof(int);
    if (ws_size < need_bytes) return;

    k_gemm<0><<<dim3(128, 8), 256, 0, stream>>>(F, T, Kb, cpart, nullptr, nullptr, flags);
    k_init1<<<8, 128, 0, stream>>>(cpart, ktu0);
    k_init2<<<400, 256, 0, stream>>>(slots, done, flags);
    k_persist<<<PBLK, PTHR, 0, stream>>>(Kb, ratios, ktu0, slots, utmp, vcom,
                                         flags, done);
    k_gemm<1><<<dim3(128, 8), 256, 0, stream>>>(F, T, out, nullptr, vcom, utmp, flags);
}